// Round 1
// baseline (1200.279 us; speedup 1.0000x reference)
//
#include <hip/hip_runtime.h>
#include <hip/hip_bf16.h>
#include <math.h>

#define B_TOK   8192
#define DMODEL  1024
#define HIDDEN  4096
#define NCLS    1000
#define NCLSP   1024
#define NEXP    8
#define SMAXL   9216    // per ranked list: 8192 + 8*127 pad, rounded to 128
#define TM      128
#define TN      128
#define BK      32

typedef __bf16 bf16x8_t __attribute__((ext_vector_type(8)));
typedef float  f32x4_t  __attribute__((ext_vector_type(4)));

// async 16B global->LDS (lds dest must be wave-uniform base + lane*16)
#define GLL16(gp, lp) __builtin_amdgcn_global_load_lds( \
    (const __attribute__((address_space(1))) void*)(gp), \
    (__attribute__((address_space(3))) void*)(lp), 16, 0, 0)

static __device__ __forceinline__ unsigned short f2b(float f) {
  union { float f; unsigned int u; } v; v.f = f;
  unsigned int r = v.u + 0x7FFFu + ((v.u >> 16) & 1u);   // RTNE
  return (unsigned short)(r >> 16);
}

// ------- transpose + convert: src[R][C] fp32 -> dst[C_pad][R] bf16 (per expert z) -------
__global__ void transpose_cvt_kernel(const float* __restrict__ src, unsigned short* __restrict__ dst,
                                     int R, int C, long src_stride, long dst_stride) {
  __shared__ float tile[32][33];
  src += (long)blockIdx.z * src_stride;
  dst += (long)blockIdx.z * dst_stride;
  int c0 = blockIdx.x * 32, r0 = blockIdx.y * 32;
  int tx = threadIdx.x, ty = threadIdx.y;     // (32,8)
  #pragma unroll
  for (int i = 0; i < 32; i += 8) {
    int r = r0 + ty + i, c = c0 + tx;
    tile[ty + i][tx] = (c < C) ? src[(long)r * C + c] : 0.0f;  // R is a multiple of 32
  }
  __syncthreads();
  #pragma unroll
  for (int i = 0; i < 32; i += 8) {
    int c = c0 + ty + i, r = r0 + tx;
    dst[(long)c * R + r] = f2b(tile[tx][ty + i]);   // zero-fills the pad rows
  }
}

// ------- router: Wg staged in LDS (pad-9 rows -> 2-way-free banks), fp64 logits,
//         top-2 (first-max tie-break), softmax gates; fused x->bf16.
//         8 tokens/block (2 per wave) -> 1024 blocks so the chip has waves to
//         co-schedule (old 256-block version sat at 1 wave/SIMD, 8.9% occupancy,
//         214 us while latency-bound). launch_bounds(256,4) caps VGPR<=128 so the
//         LDS limit (4 blocks/CU = 16 waves/CU) is the binding one. Softmax uses
//         expf on the fp64-reduced logit delta (top-2 selection stays exact fp64;
//         fp64 exp() was lane-0-only but cost the whole wave its registers). -------
__global__ __launch_bounds__(256, 4) void router_kernel(
    const float* __restrict__ x, const float* __restrict__ Wg, const float* __restrict__ bg,
    unsigned short* __restrict__ xb,  // [B][D] bf16 out
    float* __restrict__ gates_out,    // [B][8] fp32
    float* __restrict__ topi_out,     // [B][2] fp32 (float-encoded ints)
    int* __restrict__ top_idx, float* __restrict__ top_gate,
    int* __restrict__ counts0, int* __restrict__ counts1) {
  __shared__ float wgs[DMODEL * 9];   // row stride 9 words: bank=(9d+e)%32 -> 2-way max
  int tid = threadIdx.x;
  const float4* wg4 = (const float4*)Wg;
  #pragma unroll
  for (int j = 0; j < 8; j++) {
    int g4 = tid + j * 256;           // 2048 float4s total
    float4 v = wg4[g4];
    int g = g4 * 4;                   // g%8 in {0,4}: float4 never straddles a row
    int a = g + (g >> 3);
    wgs[a] = v.x; wgs[a + 1] = v.y; wgs[a + 2] = v.z; wgs[a + 3] = v.w;
  }
  __syncthreads();
  int wave = tid >> 6, lane = tid & 63;
  int t0 = blockIdx.x * 8 + wave * 2;
  for (int ti = 0; ti < 2; ti++) {
    int t = t0 + ti;
    const float* xr = x + (long)t * DMODEL;
    unsigned short* xbr = xb + (long)t * DMODEL;
    double acc[NEXP];
    #pragma unroll
    for (int e = 0; e < NEXP; e++) acc[e] = 0.0;
    #pragma unroll
    for (int k = 0; k < DMODEL / 64; k++) {
      int d = lane + 64 * k;
      float xv = xr[d];               // coalesced
      xbr[d] = f2b(xv);               // coalesced 2B stores
      const float* wrow = &wgs[d * 9];
      double xd = (double)xv;
      #pragma unroll
      for (int e = 0; e < NEXP; e++) acc[e] += xd * (double)wrow[e];
    }
    #pragma unroll
    for (int off = 32; off > 0; off >>= 1) {
      #pragma unroll
      for (int e = 0; e < NEXP; e++) acc[e] += __shfl_xor(acc[e], off);
    }
    if (lane == 0) {
      #pragma unroll
      for (int e = 0; e < NEXP; e++) acc[e] += (double)bg[e];
      int i0 = 0;
      #pragma unroll
      for (int e = 1; e < NEXP; e++) if (acc[e] > acc[i0]) i0 = e;   // first-max wins
      int i1 = (i0 == 0) ? 1 : 0;
      #pragma unroll
      for (int e = 0; e < NEXP; e++) if (e != i0 && acc[e] > acc[i1]) i1 = e;
      float e1 = expf((float)(acc[i1] - acc[i0]));   // <= 0 arg: e1 in (0,1]
      float g0 = 1.0f / (1.0f + e1);
      float g1 = e1 * g0;
      #pragma unroll
      for (int e = 0; e < NEXP; e++) gates_out[t * NEXP + e] = 0.f;
      gates_out[t * NEXP + i0] = g0;
      gates_out[t * NEXP + i1] = g1;
      topi_out[t * 2 + 0] = (float)i0;
      topi_out[t * 2 + 1] = (float)i1;
      top_idx[t * 2 + 0] = i0; top_idx[t * 2 + 1] = i1;
      top_gate[t * 2 + 0] = g0; top_gate[t * 2 + 1] = g1;
      atomicAdd(&counts0[i0], 1);
      atomicAdd(&counts1[i1], 1);
    }
  }
}

// ---------------- per-expert offsets for both ranked lists, aligned to TM ----------------
__global__ void offsets_kernel(const int* __restrict__ counts, int* __restrict__ offs) {
  // counts: [0:8) counts0, [8:16) counts1 ; offs: [0:9) off0, [9:18) off1
  if (threadIdx.x == 0 && blockIdx.x == 0) {
    #pragma unroll
    for (int l = 0; l < 2; l++) {
      int cur = 0;
      for (int e = 0; e < NEXP; e++) {
        offs[l * 9 + e] = cur;
        cur = (cur + counts[l * 8 + e] + (TM - 1)) & ~(TM - 1);
      }
      offs[l * 9 + NEXP] = cur;
    }
  }
}

// ---------------- fill ranked per-expert token lists ----------------
__global__ void fill_kernel(const int* __restrict__ top_idx, const float* __restrict__ top_gate,
                            const int* __restrict__ offs, int* __restrict__ cnt2,
                            int* __restrict__ token_list, float* __restrict__ slot_gate) {
  int t = blockIdx.x * blockDim.x + threadIdx.x;
  if (t < B_TOK) {
    #pragma unroll
    for (int k = 0; k < 2; k++) {
      int e = top_idx[t * 2 + k];
      int pos = atomicAdd(&cnt2[k * 8 + e], 1);
      int slot = k * SMAXL + offs[k * 9 + e] + pos;
      token_list[slot] = t;
      slot_gate[slot] = top_gate[t * 2 + k];
    }
  }
}

// ---------------- GEMM1: h = gelu(Xg @ W1[e] + b1[e]) -> bf16 chunk buffer ----------------
// 1-D grid, bid = (no*mcount + m)*8 + ni; n = no*8+ni. XCD (bid%8) pins an n-column set
// so each W1 tile is fetched by one XCD and stays L2-resident across its m-sweep.
__global__ __launch_bounds__(256, 4) void gemm1_kernel(
    const unsigned short* __restrict__ xb,     // [B][D] bf16
    const unsigned short* __restrict__ w1t,    // [E][H][D] bf16 (n-major)
    const float* __restrict__ b1,              // [E][H] fp32
    const int* __restrict__ token_list,        // list base
    const int* __restrict__ offs,              // off list base (9 ints)
    unsigned short* __restrict__ hbuf,         // [chunk_rows][H]
    int mcount, int chunk_base) {
  __shared__ unsigned short As[TM * BK];
  __shared__ unsigned short Bs[TN * BK];
  int ni = blockIdx.x & 7;
  int rest = blockIdx.x >> 3;
  int m = rest % mcount;
  int no = rest / mcount;
  int nb = (no * 8 + ni) * TN;
  int base = chunk_base + m * TM;
  if (base >= offs[NEXP]) return;
  int e = 0;
  #pragma unroll
  for (int i = 1; i < NEXP; i++) if (base >= offs[i]) e = i;
  int tid = threadIdx.x;
  int r0 = tid >> 2, koff = (tid & 3) * 8;
  const unsigned short* ga0 = xb + (long)token_list[base + r0] * DMODEL + koff;
  const unsigned short* ga1 = xb + (long)token_list[base + 64 + r0] * DMODEL + koff;
  const unsigned short* gb0 = w1t + ((long)e * HIDDEN + nb + r0) * DMODEL + koff;
  const unsigned short* gb1 = gb0 + 64 * DMODEL;
  unsigned short* lA0 = As + tid * 8;
  unsigned short* lA1 = As + 2048 + tid * 8;
  unsigned short* lB0 = Bs + tid * 8;
  unsigned short* lB1 = Bs + 2048 + tid * 8;
  int wave = tid >> 6, lane = tid & 63;
  int wm = (wave & 1) * 64, wn = (wave >> 1) * 64;
  int lm = lane & 15, quad = lane >> 4;
  const unsigned short* pA = As + (wm + lm) * BK + quad * 8;
  const unsigned short* pB = Bs + (wn + lm) * BK + quad * 8;
  f32x4_t acc[4][4];
  #pragma unroll
  for (int i = 0; i < 4; i++) {
    #pragma unroll
    for (int j = 0; j < 4; j++) acc[i][j] = (f32x4_t){0.f, 0.f, 0.f, 0.f};
  }
  for (int k0 = 0; k0 < DMODEL; k0 += BK) {
    GLL16(ga0 + k0, lA0);
    GLL16(ga1 + k0, lA1);
    GLL16(gb0 + k0, lB0);
    GLL16(gb1 + k0, lB1);
    __syncthreads();
    bf16x8_t af[4], bfr[4];
    #pragma unroll
    for (int i = 0; i < 4; i++) {
      af[i]  = *(const bf16x8_t*)(pA + i * 16 * BK);
      bfr[i] = *(const bf16x8_t*)(pB + i * 16 * BK);
    }
    #pragma unroll
    for (int i = 0; i < 4; i++) {
      #pragma unroll
      for (int j = 0; j < 4; j++)
        acc[i][j] = __builtin_amdgcn_mfma_f32_16x16x32_bf16(af[i], bfr[j], acc[i][j], 0, 0, 0);
    }
    __syncthreads();
  }
  float bv[4];
  #pragma unroll
  for (int j = 0; j < 4; j++) bv[j] = b1[(long)e * HIDDEN + nb + wn + j * 16 + lm];
  #pragma unroll
  for (int i = 0; i < 4; i++) {
    #pragma unroll
    for (int r = 0; r < 4; r++) {
      long hrow = (long)m * TM + wm + i * 16 + quad * 4 + r;  // chunk-local
      unsigned short* hp = hbuf + hrow * HIDDEN + nb + wn + lm;
      #pragma unroll
      for (int j = 0; j < 4; j++) {
        float pre = acc[i][j][r] + bv[j];
        float g = 0.5f * pre * (1.0f + erff(pre * 0.70710678118f));  // exact GELU
        hp[j * 16] = f2b(g);
      }
    }
  }
}

// --------- GEMM2: pass0 stores out = g*(h@W2+b2); pass1 does non-atomic out += ... ---------
// 1-D grid, bid = m*8 + n. Each XCD owns one n-column: its W2 slice (1 MB/expert) stays
// L2-resident across the m-sweep.
__global__ __launch_bounds__(256, 4) void gemm2_kernel(
    const unsigned short* __restrict__ hbuf,   // [chunk_rows][H] bf16
    const unsigned short* __restrict__ w2t,    // [E][NCLSP][H] bf16 (n-major, pad rows zero)
    const float* __restrict__ b2,              // [E][NCLS] fp32
    const int* __restrict__ token_list,        // list base
    const float* __restrict__ slot_gate,       // list base
    const int* __restrict__ offs,              // off list base (9 ints)
    float* __restrict__ out,                   // [B][NCLS] fp32
    int chunk_base, int rmw) {
  __shared__ unsigned short As[TM * BK];
  __shared__ unsigned short Bs[TN * BK];
  int n = blockIdx.x & 7;
  int m = blockIdx.x >> 3;
  int base = chunk_base + m * TM;
  if (base >= offs[NEXP]) return;
  int e = 0;
  #pragma unroll
  for (int i = 1; i < NEXP; i++) if (base >= offs[i]) e = i;
  int nb = n * TN;
  int tid = threadIdx.x;
  int r0 = tid >> 2, koff = (tid & 3) * 8;
  const unsigned short* ga0 = hbuf + ((long)m * TM + r0) * HIDDEN + koff;
  const unsigned short* ga1 = ga0 + 64 * HIDDEN;
  const unsigned short* gb0 = w2t + ((long)e * NCLSP + nb + r0) * HIDDEN + koff;
  const unsigned short* gb1 = gb0 + 64 * HIDDEN;
  unsigned short* lA0 = As + tid * 8;
  unsigned short* lA1 = As + 2048 + tid * 8;
  unsigned short* lB0 = Bs + tid * 8;
  unsigned short* lB1 = Bs + 2048 + tid * 8;
  int wave = tid >> 6, lane = tid & 63;
  int wm = (wave & 1) * 64, wn = (wave >> 1) * 64;
  int lm = lane & 15, quad = lane >> 4;
  const unsigned short* pA = As + (wm + lm) * BK + quad * 8;
  const unsigned short* pB = Bs + (wn + lm) * BK + quad * 8;
  f32x4_t acc[4][4];
  #pragma unroll
  for (int i = 0; i < 4; i++) {
    #pragma unroll
    for (int j = 0; j < 4; j++) acc[i][j] = (f32x4_t){0.f, 0.f, 0.f, 0.f};
  }
  for (int k0 = 0; k0 < HIDDEN; k0 += BK) {
    GLL16(ga0 + k0, lA0);
    GLL16(ga1 + k0, lA1);
    GLL16(gb0 + k0, lB0);
    GLL16(gb1 + k0, lB1);
    __syncthreads();
    bf16x8_t af[4], bfr[4];
    #pragma unroll
    for (int i = 0; i < 4; i++) {
      af[i]  = *(const bf16x8_t*)(pA + i * 16 * BK);
      bfr[i] = *(const bf16x8_t*)(pB + i * 16 * BK);
    }
    #pragma unroll
    for (int i = 0; i < 4; i++) {
      #pragma unroll
      for (int j = 0; j < 4; j++)
        acc[i][j] = __builtin_amdgcn_mfma_f32_16x16x32_bf16(af[i], bfr[j], acc[i][j], 0, 0, 0);
    }
    __syncthreads();
  }
  int nvec[4]; float b2v[4];
  #pragma unroll
  for (int j = 0; j < 4; j++) {
    int nn = nb + wn + j * 16 + lm;
    nvec[j] = nn;
    b2v[j] = (nn < NCLS) ? b2[(long)e * NCLS + nn] : 0.f;
  }
  #pragma unroll
  for (int i = 0; i < 4; i++) {
    #pragma unroll
    for (int r = 0; r < 4; r++) {
      int slot = base + wm + i * 16 + quad * 4 + r;
      int tok = token_list[slot];
      float g = slot_gate[slot];
      if (g != 0.f) {   // padding slots have g==0
        float* op = out + (long)tok * NCLS;
        if (rmw) {
          #pragma unroll
          for (int j = 0; j < 4; j++)
            if (nvec[j] < NCLS) op[nvec[j]] += g * (acc[i][j][r] + b2v[j]);
        } else {
          #pragma unroll
          for (int j = 0; j < 4; j++)
            if (nvec[j] < NCLS) op[nvec[j]] = g * (acc[i][j][r] + b2v[j]);
        }
      }
    }
  }
}

extern "C" void kernel_launch(void* const* d_in, const int* in_sizes, int n_in,
                              void* d_out, int out_size, void* d_ws, size_t ws_size,
                              hipStream_t stream) {
  (void)in_sizes; (void)n_in; (void)out_size;
  const float* x  = (const float*)d_in[0];
  const float* Wg = (const float*)d_in[1];
  const float* bg = (const float*)d_in[2];
  const float* W1 = (const float*)d_in[3];
  const float* b1 = (const float*)d_in[4];
  const float* W2 = (const float*)d_in[5];
  const float* b2 = (const float*)d_in[6];

  float* out_f     = (float*)d_out;                       // [B][NCLS] fp32
  float* gates_out = out_f + (size_t)B_TOK * NCLS;        // [B][8] fp32
  float* topi_out  = gates_out + (size_t)B_TOK * NEXP;    // [B][2] fp32

  char* p = (char*)d_ws;
  auto alloc = [&](size_t bytes) { char* r = p; p += (bytes + 255) & ~(size_t)255; return r; };
  unsigned short* xb  = (unsigned short*)alloc((size_t)B_TOK * DMODEL * 2);         // 16 MB
  unsigned short* w1t = (unsigned short*)alloc((size_t)NEXP * HIDDEN * DMODEL * 2); // 64 MB
  unsigned short* w2t = (unsigned short*)alloc((size_t)NEXP * NCLSP * HIDDEN * 2);  // 64 MB
  char* zstart = p;
  int*   token_list = (int*)alloc((size_t)2 * SMAXL * 4);
  float* slot_gate  = (float*)alloc((size_t)2 * SMAXL * 4);
  int*   counts     = (int*)alloc(64 * 4);   // counts0[0:8], counts1[8:16], cnt2[16:32]
  char* zend = p;
  int*   offs     = (int*)alloc(32 * 4);     // off0[0:9], off1[9:18]
  int*   top_idx  = (int*)alloc((size_t)B_TOK * 2 * 4);
  float* top_gate = (float*)alloc((size_t)B_TOK * 2 * 4);
  unsigned short* hbuf = (unsigned short*)p;
  size_t used = (size_t)(p - (char*)d_ws);
  size_t hbytes = (ws_size > used) ? (ws_size - used) : 0;
  long hrows = (long)(hbytes / ((size_t)HIDDEN * 2));
  hrows &= ~(long)(TM - 1);
  if (hrows > SMAXL) hrows = SMAXL;
  if (hrows < TM) hrows = TM;   // ws too small: best effort
  int* cnt2 = counts + 16;

  // Zero routing scratch (harness poisons ws with 0xAA). out needs no memset:
  // pass-0 gemm2 overwrites every (t, c<NCLS) element exactly once.
  hipMemsetAsync(zstart, 0, (size_t)(zend - zstart), stream);

  dim3 tb(32, 8);
  transpose_cvt_kernel<<<dim3(HIDDEN / 32, DMODEL / 32, NEXP), tb, 0, stream>>>(
      W1, w1t, DMODEL, HIDDEN, (long)DMODEL * HIDDEN, (long)HIDDEN * DMODEL);
  transpose_cvt_kernel<<<dim3(NCLSP / 32, HIDDEN / 32, NEXP), tb, 0, stream>>>(
      W2, w2t, HIDDEN, NCLS, (long)HIDDEN * NCLS, (long)NCLSP * HIDDEN);
  router_kernel<<<B_TOK / 8, 256, 0, stream>>>(x, Wg, bg, xb, gates_out, topi_out,
                                               top_idx, top_gate, counts, counts + 8);
  offsets_kernel<<<1, 64, 0, stream>>>(counts, offs);
  fill_kernel<<<B_TOK / 256, 256, 0, stream>>>(top_idx, top_gate, offs, cnt2,
                                               token_list, slot_gate);
  for (int pass = 0; pass < 2; pass++) {
    const int* tl = token_list + pass * SMAXL;
    const float* sg = slot_gate + pass * SMAXL;
    const int* of = offs + pass * 9;
    for (long cb = 0; cb < SMAXL; cb += hrows) {
      long rows = SMAXL - cb; if (rows > hrows) rows = hrows;
      int mcount = (int)(rows / TM);
      gemm1_kernel<<<dim3((unsigned)(mcount * (HIDDEN / TN))), 256, 0, stream>>>(
          xb, w1t, b1, tl, of, hbuf, mcount, (int)cb);
      gemm2_kernel<<<dim3((unsigned)(mcount * (NCLSP / TN))), 256, 0, stream>>>(
          hbuf, w2t, b2, tl, sg, of, out_f, (int)cb, pass);
    }
  }
}

// Round 2
// 1123.518 us; speedup vs baseline: 1.0683x; 1.0683x over previous
//
#include <hip/hip_runtime.h>
#include <hip/hip_bf16.h>
#include <math.h>

#define B_TOK   8192
#define DMODEL  1024
#define HIDDEN  4096
#define NCLS    1000
#define NCLSP   1024
#define NEXP    8
#define SMAXL   9216    // per ranked list: 8192 + 8*127 pad, rounded to 128
#define TM      128
#define TN      128
#define BK      32

typedef __bf16 bf16x8_t __attribute__((ext_vector_type(8)));
typedef float  f32x4_t  __attribute__((ext_vector_type(4)));

// async 16B global->LDS (lds dest must be wave-uniform base + lane*16)
#define GLL16(gp, lp) __builtin_amdgcn_global_load_lds( \
    (const __attribute__((address_space(1))) void*)(gp), \
    (__attribute__((address_space(3))) void*)(lp), 16, 0, 0)

static __device__ __forceinline__ unsigned short f2b(float f) {
  union { float f; unsigned int u; } v; v.f = f;
  unsigned int r = v.u + 0x7FFFu + ((v.u >> 16) & 1u);   // RTNE
  return (unsigned short)(r >> 16);
}

// ------- transpose + convert: src[R][C] fp32 -> dst[C_pad][R] bf16 (per expert z) -------
__global__ void transpose_cvt_kernel(const float* __restrict__ src, unsigned short* __restrict__ dst,
                                     int R, int C, long src_stride, long dst_stride) {
  __shared__ float tile[32][33];
  src += (long)blockIdx.z * src_stride;
  dst += (long)blockIdx.z * dst_stride;
  int c0 = blockIdx.x * 32, r0 = blockIdx.y * 32;
  int tx = threadIdx.x, ty = threadIdx.y;     // (32,8)
  #pragma unroll
  for (int i = 0; i < 32; i += 8) {
    int r = r0 + ty + i, c = c0 + tx;
    tile[ty + i][tx] = (c < C) ? src[(long)r * C + c] : 0.0f;  // R is a multiple of 32
  }
  __syncthreads();
  #pragma unroll
  for (int i = 0; i < 32; i += 8) {
    int c = c0 + ty + i, r = r0 + tx;
    dst[(long)c * R + r] = f2b(tile[tx][ty + i]);   // zero-fills the pad rows
  }
}

// ------- router: Wg staged in LDS (pad-9 rows -> 2-way-free banks), fp64 logits,
//         top-2 (first-max tie-break), softmax gates; fused x->bf16.
//         8 tokens/block (2 per wave) -> 1024 blocks for latency hiding.
//         NO min-waves launch_bounds: round-1's (256,4) cap crushed VGPR to 64 and
//         spilled the fp64 acc[8] to scratch (FETCH+WRITE ballooned 35->398 MB,
//         286 us). Compiler's natural ~160 VGPR -> 3 waves/SIMD, no spill. -------
__global__ __launch_bounds__(256) void router_kernel(
    const float* __restrict__ x, const float* __restrict__ Wg, const float* __restrict__ bg,
    unsigned short* __restrict__ xb,  // [B][D] bf16 out
    float* __restrict__ gates_out,    // [B][8] fp32
    float* __restrict__ topi_out,     // [B][2] fp32 (float-encoded ints)
    int* __restrict__ top_idx, float* __restrict__ top_gate,
    int* __restrict__ counts0, int* __restrict__ counts1) {
  __shared__ float wgs[DMODEL * 9];   // row stride 9 words: bank=(9d+e)%32 -> 2-way max
  int tid = threadIdx.x;
  const float4* wg4 = (const float4*)Wg;
  #pragma unroll
  for (int j = 0; j < 8; j++) {
    int g4 = tid + j * 256;           // 2048 float4s total
    float4 v = wg4[g4];
    int g = g4 * 4;                   // g%8 in {0,4}: float4 never straddles a row
    int a = g + (g >> 3);
    wgs[a] = v.x; wgs[a + 1] = v.y; wgs[a + 2] = v.z; wgs[a + 3] = v.w;
  }
  __syncthreads();
  int wave = tid >> 6, lane = tid & 63;
  int t0 = blockIdx.x * 8 + wave * 2;
  for (int ti = 0; ti < 2; ti++) {
    int t = t0 + ti;
    const float* xr = x + (long)t * DMODEL;
    unsigned short* xbr = xb + (long)t * DMODEL;
    double acc[NEXP];
    #pragma unroll
    for (int e = 0; e < NEXP; e++) acc[e] = 0.0;
    #pragma unroll
    for (int k = 0; k < DMODEL / 64; k++) {
      int d = lane + 64 * k;
      float xv = xr[d];               // coalesced
      xbr[d] = f2b(xv);               // coalesced 2B stores
      const float* wrow = &wgs[d * 9];
      double xd = (double)xv;
      #pragma unroll
      for (int e = 0; e < NEXP; e++) acc[e] += xd * (double)wrow[e];
    }
    #pragma unroll
    for (int off = 32; off > 0; off >>= 1) {
      #pragma unroll
      for (int e = 0; e < NEXP; e++) acc[e] += __shfl_xor(acc[e], off);
    }
    if (lane == 0) {
      #pragma unroll
      for (int e = 0; e < NEXP; e++) acc[e] += (double)bg[e];
      int i0 = 0;
      #pragma unroll
      for (int e = 1; e < NEXP; e++) if (acc[e] > acc[i0]) i0 = e;   // first-max wins
      int i1 = (i0 == 0) ? 1 : 0;
      #pragma unroll
      for (int e = 0; e < NEXP; e++) if (e != i0 && acc[e] > acc[i1]) i1 = e;
      float e1 = expf((float)(acc[i1] - acc[i0]));   // <= 0 arg: e1 in (0,1]
      float g0 = 1.0f / (1.0f + e1);
      float g1 = e1 * g0;
      #pragma unroll
      for (int e = 0; e < NEXP; e++) gates_out[t * NEXP + e] = 0.f;
      gates_out[t * NEXP + i0] = g0;
      gates_out[t * NEXP + i1] = g1;
      topi_out[t * 2 + 0] = (float)i0;
      topi_out[t * 2 + 1] = (float)i1;
      top_idx[t * 2 + 0] = i0; top_idx[t * 2 + 1] = i1;
      top_gate[t * 2 + 0] = g0; top_gate[t * 2 + 1] = g1;
      atomicAdd(&counts0[i0], 1);
      atomicAdd(&counts1[i1], 1);
    }
  }
}

// ---------------- per-expert offsets for both ranked lists, aligned to TM ----------------
__global__ void offsets_kernel(const int* __restrict__ counts, int* __restrict__ offs) {
  // counts: [0:8) counts0, [8:16) counts1 ; offs: [0:9) off0, [9:18) off1
  if (threadIdx.x == 0 && blockIdx.x == 0) {
    #pragma unroll
    for (int l = 0; l < 2; l++) {
      int cur = 0;
      for (int e = 0; e < NEXP; e++) {
        offs[l * 9 + e] = cur;
        cur = (cur + counts[l * 8 + e] + (TM - 1)) & ~(TM - 1);
      }
      offs[l * 9 + NEXP] = cur;
    }
  }
}

// ---------------- fill ranked per-expert token lists ----------------
__global__ void fill_kernel(const int* __restrict__ top_idx, const float* __restrict__ top_gate,
                            const int* __restrict__ offs, int* __restrict__ cnt2,
                            int* __restrict__ token_list, float* __restrict__ slot_gate) {
  int t = blockIdx.x * blockDim.x + threadIdx.x;
  if (t < B_TOK) {
    #pragma unroll
    for (int k = 0; k < 2; k++) {
      int e = top_idx[t * 2 + k];
      int pos = atomicAdd(&cnt2[k * 8 + e], 1);
      int slot = k * SMAXL + offs[k * 9 + e] + pos;
      token_list[slot] = t;
      slot_gate[slot] = top_gate[t * 2 + k];
    }
  }
}

// ---------------- GEMM1: h = gelu(Xg @ W1[e] + b1[e]) -> bf16 chunk buffer ----------------
// 1-D grid, bid = (no*mcount + m)*8 + ni; n = no*8+ni. XCD (bid%8) pins an n-column set
// so each W1 tile is fetched by one XCD and stays L2-resident across its m-sweep.
__global__ __launch_bounds__(256, 4) void gemm1_kernel(
    const unsigned short* __restrict__ xb,     // [B][D] bf16
    const unsigned short* __restrict__ w1t,    // [E][H][D] bf16 (n-major)
    const float* __restrict__ b1,              // [E][H] fp32
    const int* __restrict__ token_list,        // list base
    const int* __restrict__ offs,              // off list base (9 ints)
    unsigned short* __restrict__ hbuf,         // [chunk_rows][H]
    int mcount, int chunk_base) {
  __shared__ unsigned short As[TM * BK];
  __shared__ unsigned short Bs[TN * BK];
  int ni = blockIdx.x & 7;
  int rest = blockIdx.x >> 3;
  int m = rest % mcount;
  int no = rest / mcount;
  int nb = (no * 8 + ni) * TN;
  int base = chunk_base + m * TM;
  if (base >= offs[NEXP]) return;
  int e = 0;
  #pragma unroll
  for (int i = 1; i < NEXP; i++) if (base >= offs[i]) e = i;
  int tid = threadIdx.x;
  int r0 = tid >> 2, koff = (tid & 3) * 8;
  const unsigned short* ga0 = xb + (long)token_list[base + r0] * DMODEL + koff;
  const unsigned short* ga1 = xb + (long)token_list[base + 64 + r0] * DMODEL + koff;
  const unsigned short* gb0 = w1t + ((long)e * HIDDEN + nb + r0) * DMODEL + koff;
  const unsigned short* gb1 = gb0 + 64 * DMODEL;
  unsigned short* lA0 = As + tid * 8;
  unsigned short* lA1 = As + 2048 + tid * 8;
  unsigned short* lB0 = Bs + tid * 8;
  unsigned short* lB1 = Bs + 2048 + tid * 8;
  int wave = tid >> 6, lane = tid & 63;
  int wm = (wave & 1) * 64, wn = (wave >> 1) * 64;
  int lm = lane & 15, quad = lane >> 4;
  const unsigned short* pA = As + (wm + lm) * BK + quad * 8;
  const unsigned short* pB = Bs + (wn + lm) * BK + quad * 8;
  f32x4_t acc[4][4];
  #pragma unroll
  for (int i = 0; i < 4; i++) {
    #pragma unroll
    for (int j = 0; j < 4; j++) acc[i][j] = (f32x4_t){0.f, 0.f, 0.f, 0.f};
  }
  for (int k0 = 0; k0 < DMODEL; k0 += BK) {
    GLL16(ga0 + k0, lA0);
    GLL16(ga1 + k0, lA1);
    GLL16(gb0 + k0, lB0);
    GLL16(gb1 + k0, lB1);
    __syncthreads();
    bf16x8_t af[4], bfr[4];
    #pragma unroll
    for (int i = 0; i < 4; i++) {
      af[i]  = *(const bf16x8_t*)(pA + i * 16 * BK);
      bfr[i] = *(const bf16x8_t*)(pB + i * 16 * BK);
    }
    #pragma unroll
    for (int i = 0; i < 4; i++) {
      #pragma unroll
      for (int j = 0; j < 4; j++)
        acc[i][j] = __builtin_amdgcn_mfma_f32_16x16x32_bf16(af[i], bfr[j], acc[i][j], 0, 0, 0);
    }
    __syncthreads();
  }
  float bv[4];
  #pragma unroll
  for (int j = 0; j < 4; j++) bv[j] = b1[(long)e * HIDDEN + nb + wn + j * 16 + lm];
  #pragma unroll
  for (int i = 0; i < 4; i++) {
    #pragma unroll
    for (int r = 0; r < 4; r++) {
      long hrow = (long)m * TM + wm + i * 16 + quad * 4 + r;  // chunk-local
      unsigned short* hp = hbuf + hrow * HIDDEN + nb + wn + lm;
      #pragma unroll
      for (int j = 0; j < 4; j++) {
        float pre = acc[i][j][r] + bv[j];
        float g = 0.5f * pre * (1.0f + erff(pre * 0.70710678118f));  // exact GELU
        hp[j * 16] = f2b(g);
      }
    }
  }
}

// --------- GEMM2: pass0 stores out = g*(h@W2+b2); pass1 does non-atomic out += ... ---------
// 1-D grid, bid = m*8 + n. Each XCD owns one n-column: its W2 slice (1 MB/expert) stays
// L2-resident across the m-sweep.
__global__ __launch_bounds__(256, 4) void gemm2_kernel(
    const unsigned short* __restrict__ hbuf,   // [chunk_rows][H] bf16
    const unsigned short* __restrict__ w2t,    // [E][NCLSP][H] bf16 (n-major, pad rows zero)
    const float* __restrict__ b2,              // [E][NCLS] fp32
    const int* __restrict__ token_list,        // list base
    const float* __restrict__ slot_gate,       // list base
    const int* __restrict__ offs,              // off list base (9 ints)
    float* __restrict__ out,                   // [B][NCLS] fp32
    int chunk_base, int rmw) {
  __shared__ unsigned short As[TM * BK];
  __shared__ unsigned short Bs[TN * BK];
  int n = blockIdx.x & 7;
  int m = blockIdx.x >> 3;
  int base = chunk_base + m * TM;
  if (base >= offs[NEXP]) return;
  int e = 0;
  #pragma unroll
  for (int i = 1; i < NEXP; i++) if (base >= offs[i]) e = i;
  int nb = n * TN;
  int tid = threadIdx.x;
  int r0 = tid >> 2, koff = (tid & 3) * 8;
  const unsigned short* ga0 = hbuf + ((long)m * TM + r0) * HIDDEN + koff;
  const unsigned short* ga1 = ga0 + 64 * HIDDEN;
  const unsigned short* gb0 = w2t + ((long)e * NCLSP + nb + r0) * HIDDEN + koff;
  const unsigned short* gb1 = gb0 + 64 * HIDDEN;
  unsigned short* lA0 = As + tid * 8;
  unsigned short* lA1 = As + 2048 + tid * 8;
  unsigned short* lB0 = Bs + tid * 8;
  unsigned short* lB1 = Bs + 2048 + tid * 8;
  int wave = tid >> 6, lane = tid & 63;
  int wm = (wave & 1) * 64, wn = (wave >> 1) * 64;
  int lm = lane & 15, quad = lane >> 4;
  const unsigned short* pA = As + (wm + lm) * BK + quad * 8;
  const unsigned short* pB = Bs + (wn + lm) * BK + quad * 8;
  f32x4_t acc[4][4];
  #pragma unroll
  for (int i = 0; i < 4; i++) {
    #pragma unroll
    for (int j = 0; j < 4; j++) acc[i][j] = (f32x4_t){0.f, 0.f, 0.f, 0.f};
  }
  for (int k0 = 0; k0 < HIDDEN; k0 += BK) {
    GLL16(ga0 + k0, lA0);
    GLL16(ga1 + k0, lA1);
    GLL16(gb0 + k0, lB0);
    GLL16(gb1 + k0, lB1);
    __syncthreads();
    bf16x8_t af[4], bfr[4];
    #pragma unroll
    for (int i = 0; i < 4; i++) {
      af[i]  = *(const bf16x8_t*)(pA + i * 16 * BK);
      bfr[i] = *(const bf16x8_t*)(pB + i * 16 * BK);
    }
    #pragma unroll
    for (int i = 0; i < 4; i++) {
      #pragma unroll
      for (int j = 0; j < 4; j++)
        acc[i][j] = __builtin_amdgcn_mfma_f32_16x16x32_bf16(af[i], bfr[j], acc[i][j], 0, 0, 0);
    }
    __syncthreads();
  }
  int nvec[4]; float b2v[4];
  #pragma unroll
  for (int j = 0; j < 4; j++) {
    int nn = nb + wn + j * 16 + lm;
    nvec[j] = nn;
    b2v[j] = (nn < NCLS) ? b2[(long)e * NCLS + nn] : 0.f;
  }
  #pragma unroll
  for (int i = 0; i < 4; i++) {
    #pragma unroll
    for (int r = 0; r < 4; r++) {
      int slot = base + wm + i * 16 + quad * 4 + r;
      int tok = token_list[slot];
      float g = slot_gate[slot];
      if (g != 0.f) {   // padding slots have g==0
        float* op = out + (long)tok * NCLS;
        if (rmw) {
          #pragma unroll
          for (int j = 0; j < 4; j++)
            if (nvec[j] < NCLS) op[nvec[j]] += g * (acc[i][j][r] + b2v[j]);
        } else {
          #pragma unroll
          for (int j = 0; j < 4; j++)
            if (nvec[j] < NCLS) op[nvec[j]] = g * (acc[i][j][r] + b2v[j]);
        }
      }
    }
  }
}

extern "C" void kernel_launch(void* const* d_in, const int* in_sizes, int n_in,
                              void* d_out, int out_size, void* d_ws, size_t ws_size,
                              hipStream_t stream) {
  (void)in_sizes; (void)n_in; (void)out_size;
  const float* x  = (const float*)d_in[0];
  const float* Wg = (const float*)d_in[1];
  const float* bg = (const float*)d_in[2];
  const float* W1 = (const float*)d_in[3];
  const float* b1 = (const float*)d_in[4];
  const float* W2 = (const float*)d_in[5];
  const float* b2 = (const float*)d_in[6];

  float* out_f     = (float*)d_out;                       // [B][NCLS] fp32
  float* gates_out = out_f + (size_t)B_TOK * NCLS;        // [B][8] fp32
  float* topi_out  = gates_out + (size_t)B_TOK * NEXP;    // [B][2] fp32

  char* p = (char*)d_ws;
  auto alloc = [&](size_t bytes) { char* r = p; p += (bytes + 255) & ~(size_t)255; return r; };
  unsigned short* xb  = (unsigned short*)alloc((size_t)B_TOK * DMODEL * 2);         // 16 MB
  unsigned short* w1t = (unsigned short*)alloc((size_t)NEXP * HIDDEN * DMODEL * 2); // 64 MB
  unsigned short* w2t = (unsigned short*)alloc((size_t)NEXP * NCLSP * HIDDEN * 2);  // 64 MB
  char* zstart = p;
  int*   token_list = (int*)alloc((size_t)2 * SMAXL * 4);
  float* slot_gate  = (float*)alloc((size_t)2 * SMAXL * 4);
  int*   counts     = (int*)alloc(64 * 4);   // counts0[0:8], counts1[8:16], cnt2[16:32]
  char* zend = p;
  int*   offs     = (int*)alloc(32 * 4);     // off0[0:9], off1[9:18]
  int*   top_idx  = (int*)alloc((size_t)B_TOK * 2 * 4);
  float* top_gate = (float*)alloc((size_t)B_TOK * 2 * 4);
  unsigned short* hbuf = (unsigned short*)p;
  size_t used = (size_t)(p - (char*)d_ws);
  size_t hbytes = (ws_size > used) ? (ws_size - used) : 0;
  long hrows = (long)(hbytes / ((size_t)HIDDEN * 2));
  hrows &= ~(long)(TM - 1);
  if (hrows > SMAXL) hrows = SMAXL;
  if (hrows < TM) hrows = TM;   // ws too small: best effort
  int* cnt2 = counts + 16;

  // Zero routing scratch (harness poisons ws with 0xAA). out needs no memset:
  // pass-0 gemm2 overwrites every (t, c<NCLS) element exactly once.
  hipMemsetAsync(zstart, 0, (size_t)(zend - zstart), stream);

  dim3 tb(32, 8);
  transpose_cvt_kernel<<<dim3(HIDDEN / 32, DMODEL / 32, NEXP), tb, 0, stream>>>(
      W1, w1t, DMODEL, HIDDEN, (long)DMODEL * HIDDEN, (long)HIDDEN * DMODEL);
  transpose_cvt_kernel<<<dim3(NCLSP / 32, HIDDEN / 32, NEXP), tb, 0, stream>>>(
      W2, w2t, HIDDEN, NCLS, (long)HIDDEN * NCLS, (long)NCLSP * HIDDEN);
  router_kernel<<<B_TOK / 8, 256, 0, stream>>>(x, Wg, bg, xb, gates_out, topi_out,
                                               top_idx, top_gate, counts, counts + 8);
  offsets_kernel<<<1, 64, 0, stream>>>(counts, offs);
  fill_kernel<<<B_TOK / 256, 256, 0, stream>>>(top_idx, top_gate, offs, cnt2,
                                               token_list, slot_gate);
  for (int pass = 0; pass < 2; pass++) {
    const int* tl = token_list + pass * SMAXL;
    const float* sg = slot_gate + pass * SMAXL;
    const int* of = offs + pass * 9;
    for (long cb = 0; cb < SMAXL; cb += hrows) {
      long rows = SMAXL - cb; if (rows > hrows) rows = hrows;
      int mcount = (int)(rows / TM);
      gemm1_kernel<<<dim3((unsigned)(mcount * (HIDDEN / TN))), 256, 0, stream>>>(
          xb, w1t, b1, tl, of, hbuf, mcount, (int)cb);
      gemm2_kernel<<<dim3((unsigned)(mcount * (NCLSP / TN))), 256, 0, stream>>>(
          hbuf, w2t, b2, tl, sg, of, out_f, (int)cb, pass);
    }
  }
}

// Round 3
// 957.925 us; speedup vs baseline: 1.2530x; 1.1729x over previous
//
#include <hip/hip_runtime.h>
#include <hip/hip_bf16.h>
#include <math.h>

#define B_TOK   8192
#define DMODEL  1024
#define HIDDEN  4096
#define NCLS    1000
#define NCLSP   1024
#define NEXP    8
#define SMAXL   9216    // per ranked list: 8192 + 8*127 pad, rounded to 128
#define TM      128
#define TN      128
#define BK      32

typedef __bf16 bf16x8_t __attribute__((ext_vector_type(8)));
typedef float  f32x4_t  __attribute__((ext_vector_type(4)));

// async 16B global->LDS (lds dest must be wave-uniform base + lane*16)
#define GLL16(gp, lp) __builtin_amdgcn_global_load_lds( \
    (const __attribute__((address_space(1))) void*)(gp), \
    (__attribute__((address_space(3))) void*)(lp), 16, 0, 0)

static __device__ __forceinline__ unsigned short f2b(float f) {
  union { float f; unsigned int u; } v; v.f = f;
  unsigned int r = v.u + 0x7FFFu + ((v.u >> 16) & 1u);   // RTNE
  return (unsigned short)(r >> 16);
}

// ------- transpose + convert: src[R][C] fp32 -> dst[C_pad][R] bf16 (per expert z) -------
__global__ void transpose_cvt_kernel(const float* __restrict__ src, unsigned short* __restrict__ dst,
                                     int R, int C, long src_stride, long dst_stride) {
  __shared__ float tile[32][33];
  src += (long)blockIdx.z * src_stride;
  dst += (long)blockIdx.z * dst_stride;
  int c0 = blockIdx.x * 32, r0 = blockIdx.y * 32;
  int tx = threadIdx.x, ty = threadIdx.y;     // (32,8)
  #pragma unroll
  for (int i = 0; i < 32; i += 8) {
    int r = r0 + ty + i, c = c0 + tx;
    tile[ty + i][tx] = (c < C) ? src[(long)r * C + c] : 0.0f;  // R is a multiple of 32
  }
  __syncthreads();
  #pragma unroll
  for (int i = 0; i < 32; i += 8) {
    int c = c0 + ty + i, r = r0 + tx;
    dst[(long)c * R + r] = f2b(tile[tx][ty + i]);   // zero-fills the pad rows
  }
}

// ------- router: Wg staged in LDS (pad-9 rows -> 2-way-free banks), fp64 logits,
//         top-2 (first-max tie-break), softmax gates; fused x->bf16.
//         8 tokens/block (2 per wave), 1024 blocks.
//         NO GLOBAL ATOMICS: rounds 0/2 showed duration (207-214 us) invariant to
//         block count with VALU/HBM/MFMA all idle -> the 16384 same-cacheline
//         atomicAdds (counts0/1 span 64 B) serialized at one L2 point and the
//         dispatch waited out the ~200 us drain. Counting moved to a histogram
//         kernel; router only emits per-token results. -------
__global__ __launch_bounds__(256) void router_kernel(
    const float* __restrict__ x, const float* __restrict__ Wg, const float* __restrict__ bg,
    unsigned short* __restrict__ xb,  // [B][D] bf16 out
    float* __restrict__ gates_out,    // [B][8] fp32
    float* __restrict__ topi_out,     // [B][2] fp32 (float-encoded ints)
    int* __restrict__ top_idx, float* __restrict__ top_gate) {
  __shared__ float wgs[DMODEL * 9];   // row stride 9 words: bank=(9d+e)%32 -> 2-way max
  int tid = threadIdx.x;
  const float4* wg4 = (const float4*)Wg;
  #pragma unroll
  for (int j = 0; j < 8; j++) {
    int g4 = tid + j * 256;           // 2048 float4s total
    float4 v = wg4[g4];
    int g = g4 * 4;                   // g%8 in {0,4}: float4 never straddles a row
    int a = g + (g >> 3);
    wgs[a] = v.x; wgs[a + 1] = v.y; wgs[a + 2] = v.z; wgs[a + 3] = v.w;
  }
  __syncthreads();
  int wave = tid >> 6, lane = tid & 63;
  int t0 = blockIdx.x * 8 + wave * 2;
  for (int ti = 0; ti < 2; ti++) {
    int t = t0 + ti;
    const float* xr = x + (long)t * DMODEL;
    unsigned short* xbr = xb + (long)t * DMODEL;
    double acc[NEXP];
    #pragma unroll
    for (int e = 0; e < NEXP; e++) acc[e] = 0.0;
    #pragma unroll
    for (int k = 0; k < DMODEL / 64; k++) {
      int d = lane + 64 * k;
      float xv = xr[d];               // coalesced
      xbr[d] = f2b(xv);               // coalesced 2B stores
      const float* wrow = &wgs[d * 9];
      double xd = (double)xv;
      #pragma unroll
      for (int e = 0; e < NEXP; e++) acc[e] += xd * (double)wrow[e];
    }
    #pragma unroll
    for (int off = 32; off > 0; off >>= 1) {
      #pragma unroll
      for (int e = 0; e < NEXP; e++) acc[e] += __shfl_xor(acc[e], off);
    }
    if (lane == 0) {
      #pragma unroll
      for (int e = 0; e < NEXP; e++) acc[e] += (double)bg[e];
      int i0 = 0;
      #pragma unroll
      for (int e = 1; e < NEXP; e++) if (acc[e] > acc[i0]) i0 = e;   // first-max wins
      int i1 = (i0 == 0) ? 1 : 0;
      #pragma unroll
      for (int e = 0; e < NEXP; e++) if (e != i0 && acc[e] > acc[i1]) i1 = e;
      float e1 = expf((float)(acc[i1] - acc[i0]));   // <= 0 arg: e1 in (0,1]
      float g0 = 1.0f / (1.0f + e1);
      float g1 = e1 * g0;
      #pragma unroll
      for (int e = 0; e < NEXP; e++) gates_out[t * NEXP + e] = 0.f;
      gates_out[t * NEXP + i0] = g0;
      gates_out[t * NEXP + i1] = g1;
      topi_out[t * 2 + 0] = (float)i0;
      topi_out[t * 2 + 1] = (float)i1;
      top_idx[t * 2 + 0] = i0; top_idx[t * 2 + 1] = i1;
      top_gate[t * 2 + 0] = g0; top_gate[t * 2 + 1] = g1;
    }
  }
}

// ------- count + offsets: one block, per-wave LDS histograms (no global atomics),
//         then TM-aligned prefix -> offs[0:9) list0, offs[9:18) list1. -------
__global__ __launch_bounds__(1024) void count_offsets_kernel(
    const int* __restrict__ top_idx, int* __restrict__ offs) {
  __shared__ int hist[16][17];   // [wave][bin], pad 17 to spread banks
  __shared__ int tot[16];
  int tid = threadIdx.x, wave = tid >> 6, lane = tid & 63;
  if (lane < 16) hist[wave][lane] = 0;
  __syncthreads();
  const int2* ti2 = (const int2*)top_idx;
  #pragma unroll
  for (int i = 0; i < B_TOK / 1024; i++) {
    int2 ee = ti2[tid + i * 1024];           // coalesced 8B loads
    atomicAdd(&hist[wave][ee.x], 1);         // LDS atomics, per-wave private bins
    atomicAdd(&hist[wave][8 + ee.y], 1);
  }
  __syncthreads();
  if (tid < 16) {
    int s = 0;
    #pragma unroll
    for (int w = 0; w < 16; w++) s += hist[w][tid];
    tot[tid] = s;
  }
  __syncthreads();
  if (tid == 0) {
    #pragma unroll
    for (int l = 0; l < 2; l++) {
      int cur = 0;
      for (int e = 0; e < NEXP; e++) {
        offs[l * 9 + e] = cur;
        cur = (cur + tot[l * 8 + e] + (TM - 1)) & ~(TM - 1);
      }
      offs[l * 9 + NEXP] = cur;
    }
  }
}

// ------- fill: two-level. LDS-atomic ranks within block; 16 global atomics/block on
//         256 B-padded counters (512 total, <=32 per cacheline vs 16384 on one). -------
__global__ __launch_bounds__(256) void fill_kernel(
    const int* __restrict__ top_idx, const float* __restrict__ top_gate,
    const int* __restrict__ offs, int* __restrict__ gcnt,   // gcnt: bin b at [b*64]
    int* __restrict__ token_list, float* __restrict__ slot_gate) {
  __shared__ int lh[16];
  __shared__ int lb[16];
  int tid = threadIdx.x;
  if (tid < 16) lh[tid] = 0;
  __syncthreads();
  int t = blockIdx.x * 256 + tid;
  int2 ee = ((const int2*)top_idx)[t];
  float2 gg = ((const float2*)top_gate)[t];
  int r0 = atomicAdd(&lh[ee.x], 1);          // LDS
  int r1 = atomicAdd(&lh[8 + ee.y], 1);      // LDS
  __syncthreads();
  if (tid < 16) lb[tid] = atomicAdd(&gcnt[tid * 64], lh[tid]);   // global, padded lines
  __syncthreads();
  int s0 = offs[ee.x] + lb[ee.x] + r0;
  token_list[s0] = t; slot_gate[s0] = gg.x;
  int s1 = SMAXL + offs[9 + ee.y] + lb[8 + ee.y] + r1;
  token_list[s1] = t; slot_gate[s1] = gg.y;
}

// ---------------- GEMM1: h = gelu(Xg @ W1[e] + b1[e]) -> bf16 chunk buffer ----------------
// 1-D grid, bid = (no*mcount + m)*8 + ni; n = no*8+ni. XCD (bid%8) pins an n-column set
// so each W1 tile is fetched by one XCD and stays L2-resident across its m-sweep.
__global__ __launch_bounds__(256, 4) void gemm1_kernel(
    const unsigned short* __restrict__ xb,     // [B][D] bf16
    const unsigned short* __restrict__ w1t,    // [E][H][D] bf16 (n-major)
    const float* __restrict__ b1,              // [E][H] fp32
    const int* __restrict__ token_list,        // list base
    const int* __restrict__ offs,              // off list base (9 ints)
    unsigned short* __restrict__ hbuf,         // [chunk_rows][H]
    int mcount, int chunk_base) {
  __shared__ unsigned short As[TM * BK];
  __shared__ unsigned short Bs[TN * BK];
  int ni = blockIdx.x & 7;
  int rest = blockIdx.x >> 3;
  int m = rest % mcount;
  int no = rest / mcount;
  int nb = (no * 8 + ni) * TN;
  int base = chunk_base + m * TM;
  if (base >= offs[NEXP]) return;
  int e = 0;
  #pragma unroll
  for (int i = 1; i < NEXP; i++) if (base >= offs[i]) e = i;
  int tid = threadIdx.x;
  int r0 = tid >> 2, koff = (tid & 3) * 8;
  const unsigned short* ga0 = xb + (long)token_list[base + r0] * DMODEL + koff;
  const unsigned short* ga1 = xb + (long)token_list[base + 64 + r0] * DMODEL + koff;
  const unsigned short* gb0 = w1t + ((long)e * HIDDEN + nb + r0) * DMODEL + koff;
  const unsigned short* gb1 = gb0 + 64 * DMODEL;
  unsigned short* lA0 = As + tid * 8;
  unsigned short* lA1 = As + 2048 + tid * 8;
  unsigned short* lB0 = Bs + tid * 8;
  unsigned short* lB1 = Bs + 2048 + tid * 8;
  int wave = tid >> 6, lane = tid & 63;
  int wm = (wave & 1) * 64, wn = (wave >> 1) * 64;
  int lm = lane & 15, quad = lane >> 4;
  const unsigned short* pA = As + (wm + lm) * BK + quad * 8;
  const unsigned short* pB = Bs + (wn + lm) * BK + quad * 8;
  f32x4_t acc[4][4];
  #pragma unroll
  for (int i = 0; i < 4; i++) {
    #pragma unroll
    for (int j = 0; j < 4; j++) acc[i][j] = (f32x4_t){0.f, 0.f, 0.f, 0.f};
  }
  for (int k0 = 0; k0 < DMODEL; k0 += BK) {
    GLL16(ga0 + k0, lA0);
    GLL16(ga1 + k0, lA1);
    GLL16(gb0 + k0, lB0);
    GLL16(gb1 + k0, lB1);
    __syncthreads();
    bf16x8_t af[4], bfr[4];
    #pragma unroll
    for (int i = 0; i < 4; i++) {
      af[i]  = *(const bf16x8_t*)(pA + i * 16 * BK);
      bfr[i] = *(const bf16x8_t*)(pB + i * 16 * BK);
    }
    #pragma unroll
    for (int i = 0; i < 4; i++) {
      #pragma unroll
      for (int j = 0; j < 4; j++)
        acc[i][j] = __builtin_amdgcn_mfma_f32_16x16x32_bf16(af[i], bfr[j], acc[i][j], 0, 0, 0);
    }
    __syncthreads();
  }
  float bv[4];
  #pragma unroll
  for (int j = 0; j < 4; j++) bv[j] = b1[(long)e * HIDDEN + nb + wn + j * 16 + lm];
  #pragma unroll
  for (int i = 0; i < 4; i++) {
    #pragma unroll
    for (int r = 0; r < 4; r++) {
      long hrow = (long)m * TM + wm + i * 16 + quad * 4 + r;  // chunk-local
      unsigned short* hp = hbuf + hrow * HIDDEN + nb + wn + lm;
      #pragma unroll
      for (int j = 0; j < 4; j++) {
        float pre = acc[i][j][r] + bv[j];
        float g = 0.5f * pre * (1.0f + erff(pre * 0.70710678118f));  // exact GELU
        hp[j * 16] = f2b(g);
      }
    }
  }
}

// --------- GEMM2: pass0 stores out = g*(h@W2+b2); pass1 does non-atomic out += ... ---------
// 1-D grid, bid = m*8 + n. Each XCD owns one n-column: its W2 slice (1 MB/expert) stays
// L2-resident across the m-sweep.
__global__ __launch_bounds__(256, 4) void gemm2_kernel(
    const unsigned short* __restrict__ hbuf,   // [chunk_rows][H] bf16
    const unsigned short* __restrict__ w2t,    // [E][NCLSP][H] bf16 (n-major, pad rows zero)
    const float* __restrict__ b2,              // [E][NCLS] fp32
    const int* __restrict__ token_list,        // list base
    const float* __restrict__ slot_gate,       // list base
    const int* __restrict__ offs,              // off list base (9 ints)
    float* __restrict__ out,                   // [B][NCLS] fp32
    int chunk_base, int rmw) {
  __shared__ unsigned short As[TM * BK];
  __shared__ unsigned short Bs[TN * BK];
  int n = blockIdx.x & 7;
  int m = blockIdx.x >> 3;
  int base = chunk_base + m * TM;
  if (base >= offs[NEXP]) return;
  int e = 0;
  #pragma unroll
  for (int i = 1; i < NEXP; i++) if (base >= offs[i]) e = i;
  int nb = n * TN;
  int tid = threadIdx.x;
  int r0 = tid >> 2, koff = (tid & 3) * 8;
  const unsigned short* ga0 = hbuf + ((long)m * TM + r0) * HIDDEN + koff;
  const unsigned short* ga1 = ga0 + 64 * HIDDEN;
  const unsigned short* gb0 = w2t + ((long)e * NCLSP + nb + r0) * HIDDEN + koff;
  const unsigned short* gb1 = gb0 + 64 * HIDDEN;
  unsigned short* lA0 = As + tid * 8;
  unsigned short* lA1 = As + 2048 + tid * 8;
  unsigned short* lB0 = Bs + tid * 8;
  unsigned short* lB1 = Bs + 2048 + tid * 8;
  int wave = tid >> 6, lane = tid & 63;
  int wm = (wave & 1) * 64, wn = (wave >> 1) * 64;
  int lm = lane & 15, quad = lane >> 4;
  const unsigned short* pA = As + (wm + lm) * BK + quad * 8;
  const unsigned short* pB = Bs + (wn + lm) * BK + quad * 8;
  f32x4_t acc[4][4];
  #pragma unroll
  for (int i = 0; i < 4; i++) {
    #pragma unroll
    for (int j = 0; j < 4; j++) acc[i][j] = (f32x4_t){0.f, 0.f, 0.f, 0.f};
  }
  for (int k0 = 0; k0 < HIDDEN; k0 += BK) {
    GLL16(ga0 + k0, lA0);
    GLL16(ga1 + k0, lA1);
    GLL16(gb0 + k0, lB0);
    GLL16(gb1 + k0, lB1);
    __syncthreads();
    bf16x8_t af[4], bfr[4];
    #pragma unroll
    for (int i = 0; i < 4; i++) {
      af[i]  = *(const bf16x8_t*)(pA + i * 16 * BK);
      bfr[i] = *(const bf16x8_t*)(pB + i * 16 * BK);
    }
    #pragma unroll
    for (int i = 0; i < 4; i++) {
      #pragma unroll
      for (int j = 0; j < 4; j++)
        acc[i][j] = __builtin_amdgcn_mfma_f32_16x16x32_bf16(af[i], bfr[j], acc[i][j], 0, 0, 0);
    }
    __syncthreads();
  }
  int nvec[4]; float b2v[4];
  #pragma unroll
  for (int j = 0; j < 4; j++) {
    int nn = nb + wn + j * 16 + lm;
    nvec[j] = nn;
    b2v[j] = (nn < NCLS) ? b2[(long)e * NCLS + nn] : 0.f;
  }
  #pragma unroll
  for (int i = 0; i < 4; i++) {
    #pragma unroll
    for (int r = 0; r < 4; r++) {
      int slot = base + wm + i * 16 + quad * 4 + r;
      int tok = token_list[slot];
      float g = slot_gate[slot];
      if (g != 0.f) {   // padding slots have g==0
        float* op = out + (long)tok * NCLS;
        if (rmw) {
          #pragma unroll
          for (int j = 0; j < 4; j++)
            if (nvec[j] < NCLS) op[nvec[j]] += g * (acc[i][j][r] + b2v[j]);
        } else {
          #pragma unroll
          for (int j = 0; j < 4; j++)
            if (nvec[j] < NCLS) op[nvec[j]] = g * (acc[i][j][r] + b2v[j]);
        }
      }
    }
  }
}

extern "C" void kernel_launch(void* const* d_in, const int* in_sizes, int n_in,
                              void* d_out, int out_size, void* d_ws, size_t ws_size,
                              hipStream_t stream) {
  (void)in_sizes; (void)n_in; (void)out_size;
  const float* x  = (const float*)d_in[0];
  const float* Wg = (const float*)d_in[1];
  const float* bg = (const float*)d_in[2];
  const float* W1 = (const float*)d_in[3];
  const float* b1 = (const float*)d_in[4];
  const float* W2 = (const float*)d_in[5];
  const float* b2 = (const float*)d_in[6];

  float* out_f     = (float*)d_out;                       // [B][NCLS] fp32
  float* gates_out = out_f + (size_t)B_TOK * NCLS;        // [B][8] fp32
  float* topi_out  = gates_out + (size_t)B_TOK * NEXP;    // [B][2] fp32

  char* p = (char*)d_ws;
  auto alloc = [&](size_t bytes) { char* r = p; p += (bytes + 255) & ~(size_t)255; return r; };
  unsigned short* xb  = (unsigned short*)alloc((size_t)B_TOK * DMODEL * 2);         // 16 MB
  unsigned short* w1t = (unsigned short*)alloc((size_t)NEXP * HIDDEN * DMODEL * 2); // 64 MB
  unsigned short* w2t = (unsigned short*)alloc((size_t)NEXP * NCLSP * HIDDEN * 2);  // 64 MB
  char* zstart = p;
  int*   token_list = (int*)alloc((size_t)2 * SMAXL * 4);
  float* slot_gate  = (float*)alloc((size_t)2 * SMAXL * 4);
  int*   gcnt       = (int*)alloc(16 * 64 * 4);   // 16 bins, 256 B apart
  char* zend = p;
  int*   offs     = (int*)alloc(32 * 4);     // off0[0:9], off1[9:18]
  int*   top_idx  = (int*)alloc((size_t)B_TOK * 2 * 4);
  float* top_gate = (float*)alloc((size_t)B_TOK * 2 * 4);
  unsigned short* hbuf = (unsigned short*)p;
  size_t used = (size_t)(p - (char*)d_ws);
  size_t hbytes = (ws_size > used) ? (ws_size - used) : 0;
  long hrows = (long)(hbytes / ((size_t)HIDDEN * 2));
  hrows &= ~(long)(TM - 1);
  if (hrows > SMAXL) hrows = SMAXL;
  if (hrows < TM) hrows = TM;   // ws too small: best effort

  // Zero routing scratch (harness poisons ws with 0xAA). out needs no memset:
  // pass-0 gemm2 overwrites every (t, c<NCLS) element exactly once.
  hipMemsetAsync(zstart, 0, (size_t)(zend - zstart), stream);

  dim3 tb(32, 8);
  transpose_cvt_kernel<<<dim3(HIDDEN / 32, DMODEL / 32, NEXP), tb, 0, stream>>>(
      W1, w1t, DMODEL, HIDDEN, (long)DMODEL * HIDDEN, (long)HIDDEN * DMODEL);
  transpose_cvt_kernel<<<dim3(NCLSP / 32, HIDDEN / 32, NEXP), tb, 0, stream>>>(
      W2, w2t, HIDDEN, NCLS, (long)HIDDEN * NCLS, (long)NCLSP * HIDDEN);
  router_kernel<<<B_TOK / 8, 256, 0, stream>>>(x, Wg, bg, xb, gates_out, topi_out,
                                               top_idx, top_gate);
  count_offsets_kernel<<<1, 1024, 0, stream>>>(top_idx, offs);
  fill_kernel<<<B_TOK / 256, 256, 0, stream>>>(top_idx, top_gate, offs, gcnt,
                                               token_list, slot_gate);
  for (int pass = 0; pass < 2; pass++) {
    const int* tl = token_list + pass * SMAXL;
    const float* sg = slot_gate + pass * SMAXL;
    const int* of = offs + pass * 9;
    for (long cb = 0; cb < SMAXL; cb += hrows) {
      long rows = SMAXL - cb; if (rows > hrows) rows = hrows;
      int mcount = (int)(rows / TM);
      gemm1_kernel<<<dim3((unsigned)(mcount * (HIDDEN / TN))), 256, 0, stream>>>(
          xb, w1t, b1, tl, of, hbuf, mcount, (int)cb);
      gemm2_kernel<<<dim3((unsigned)(mcount * (NCLSP / TN))), 256, 0, stream>>>(
          hbuf, w2t, b2, tl, sg, of, out_f, (int)cb, pass);
    }
  }
}